// Round 8
// baseline (44.515 us; speedup 1.0000x reference)
//
#include <hip/hip_runtime.h>

#define DIN  128
#define DOUT 32

typedef __attribute__((ext_vector_type(8))) short bf16x8;   // 8 bf16 = 4 VGPRs
typedef __attribute__((ext_vector_type(4))) float f32x4;

// f32 -> bf16 (RNE), manual
__device__ __forceinline__ unsigned int f2b(float f) {
    unsigned int u = __float_as_uint(f);
    return (u + 0x7fffu + ((u >> 16) & 1u)) >> 16;
}
// packed f32x2 -> bf16x2 (RNE), hardware
__device__ __forceinline__ unsigned int cvtpk(float lo, float hi) {
    unsigned int r;
    asm("v_cvt_pk_bf16_f32 %0, %1, %2" : "=v"(r) : "v"(lo), "v"(hi));
    return r;
}

union FragU { bf16x8 v; unsigned int u[4]; };

// ---------------- Kernel 1: {tbl0,tbl1} = bf16(H @ W) via MFMA --------------
// Same MFMA structure as round 7 (16 rows/wave, 6.1 waves/SIMD), but stores
// the result column-split: tbl0 = HW[:,0:16], tbl1 = HW[:,16:32] (3.2 MB each,
// per-XCD-L2-resident for the SpMM passes).
__global__ __launch_bounds__(256) void gemm_mfma_kernel(
    const float* __restrict__ H, const float* __restrict__ W,
    unsigned short* __restrict__ tbl0, unsigned short* __restrict__ tbl1, int n)
{
    const int lane = threadIdx.x & 63;
    const int w    = threadIdx.x >> 6;
    int rb = blockIdx.x * 64 + w * 16;
    if (rb + 16 > n) rb = n - 16;      // tail overlap: identical values, benign
    const int lr = lane & 15;
    const int kh = lane >> 4;          // 0..3

    // ---- B fragments from W (L2/L1-hot) ----
    bf16x8 bfrag[2][4];
    #pragma unroll
    for (int ct = 0; ct < 2; ++ct) {
        #pragma unroll
        for (int ks = 0; ks < 4; ++ks) {
            const int col = ct * 16 + lr;
            const int k0  = ks * 32 + kh * 8;
            float f[8];
            #pragma unroll
            for (int j = 0; j < 8; ++j) f[j] = W[(k0 + j) * DOUT + col];
            FragU fu;
            fu.u[0] = cvtpk(f[0], f[1]); fu.u[1] = cvtpk(f[2], f[3]);
            fu.u[2] = cvtpk(f[4], f[5]); fu.u[3] = cvtpk(f[6], f[7]);
            bfrag[ct][ks] = fu.v;
        }
    }

    // ---- A fragments: 16 rows, K=128 ----
    const float* __restrict__ hp = H + (size_t)(rb + lr) * DIN;
    bf16x8 afrag[4];
    #pragma unroll
    for (int ks = 0; ks < 4; ++ks) {
        const int k0 = ks * 32 + kh * 8;
        const float4 lo = *reinterpret_cast<const float4*>(hp + k0);
        const float4 hi = *reinterpret_cast<const float4*>(hp + k0 + 4);
        FragU fu;
        fu.u[0] = cvtpk(lo.x, lo.y); fu.u[1] = cvtpk(lo.z, lo.w);
        fu.u[2] = cvtpk(hi.x, hi.y); fu.u[3] = cvtpk(hi.z, hi.w);
        afrag[ks] = fu.v;
    }

    f32x4 acc[2] = {(f32x4){0.f,0.f,0.f,0.f}, (f32x4){0.f,0.f,0.f,0.f}};
    #pragma unroll
    for (int ct = 0; ct < 2; ++ct)
        #pragma unroll
        for (int ks = 0; ks < 4; ++ks)
            acc[ct] = __builtin_amdgcn_mfma_f32_16x16x32_bf16(
                afrag[ks], bfrag[ct][ks], acc[ct], 0, 0, 0);

    // ---- split store: C/D col=lane&15, row=(lane>>4)*4+reg ----
    #pragma unroll
    for (int ct = 0; ct < 2; ++ct) {
        unsigned short* __restrict__ t = ct ? tbl1 : tbl0;
        #pragma unroll
        for (int r = 0; r < 4; ++r) {
            const int row = rb + kh * 4 + r;
            t[(size_t)row * 16 + lr] = (unsigned short)f2b(acc[ct][r]);
        }
    }
}

// ---------------- Kernel 2: half-column SpMM pass ---------------------------
// out[:, half*16 .. half*16+15] = A @ tbl_half. Table is 3.2 MB -> resident
// in each XCD's 4 MB L2; gathers are ~all L2 hits (each row reused ~16x).
// 64 rows/block, 4 threads/row (uint2 = 4 bf16 cols each). colIdx/val staged
// in LDS so the gather is the only VMEM op in the edge loop.
#define SROWS 64
__global__ __launch_bounds__(256) void spmm_half_kernel(
    const unsigned short* __restrict__ tblu, const int* __restrict__ rowPtr,
    const int* __restrict__ colIdx, const float* __restrict__ val,
    float* __restrict__ out, int n, int half)
{
    __shared__ int   sPtr[SROWS + 1];
    __shared__ int   sIdx[1024];
    __shared__ float sVal[1024];

    const uint2* __restrict__ tbl = reinterpret_cast<const uint2*>(tblu);
    const int tid = threadIdx.x;
    const int r0  = blockIdx.x * SROWS;

    if (tid <= SROWS) {
        int rr = r0 + tid;
        if (rr > n) rr = n;
        sPtr[tid] = rowPtr[rr];
    }
    __syncthreads();

    const int eBase0 = sPtr[0];
    const int eEnd   = sPtr[SROWS];
    const int lrow   = tid >> 2;         // 0..63
    const int cg     = tid & 3;          // 0..3 (4 bf16 cols each)
    const int row    = r0 + lrow;
    const bool active = row < n;
    const int myS = active ? sPtr[lrow]     : 0;
    const int myE = active ? sPtr[lrow + 1] : 0;

    float a0 = 0.f, a1 = 0.f, a2 = 0.f, a3 = 0.f;

    for (int base = eBase0; base < eEnd; base += 1024) {
        const int cnt = min(1024, eEnd - base);
        if (base != eBase0) __syncthreads();
        for (int i = tid; i < cnt; i += 256) {
            sIdx[i] = colIdx[base + i];
            sVal[i] = val[base + i];
        }
        __syncthreads();

        const int js = max(myS, base) - base;
        const int je = min(myE, base + cnt) - base;
        #pragma unroll 8
        for (int j = js; j < je; ++j) {
            const int   c = sIdx[j];
            const float v = sVal[j];
            const uint2 g = tbl[(size_t)c * 4 + cg];
            a0 = fmaf(v, __uint_as_float(g.x << 16), a0);
            a1 = fmaf(v, __uint_as_float(g.x & 0xffff0000u), a1);
            a2 = fmaf(v, __uint_as_float(g.y << 16), a2);
            a3 = fmaf(v, __uint_as_float(g.y & 0xffff0000u), a3);
        }
    }

    if (active) {
        reinterpret_cast<float4*>(out)[(size_t)row * (DOUT / 4) + half * 4 + cg] =
            make_float4(a0, a1, a2, a3);
    }
}

// ---------------- Fallback: fused f32 (ws too small or n < 16) --------------
__global__ __launch_bounds__(256) void fused_kernel(
    const float* __restrict__ H, const float* __restrict__ W,
    const int* __restrict__ rowPtr, const int* __restrict__ colIdx,
    const float* __restrict__ val, float* __restrict__ out, int n)
{
    __shared__ float Wlds[DIN * DOUT];
    for (int i = threadIdx.x; i < DIN * DOUT; i += 256) Wlds[i] = W[i];
    __syncthreads();

    const int gid = blockIdx.x * 256 + threadIdx.x;
    const int row = gid >> 5;
    if (row >= n) return;
    const int c = gid & 31;

    const int start = rowPtr[row];
    const int end   = rowPtr[row + 1];
    float acc = 0.f;
    for (int e = start; e < end; ++e) {
        const int   cidx = colIdx[e];
        const float v    = val[e];
        const float* h = H + (size_t)cidx * DIN;
        float dot = 0.f;
        #pragma unroll 8
        for (int k = 0; k < DIN; ++k)
            dot = fmaf(h[k], Wlds[k * DOUT + c], dot);
        acc = fmaf(v, dot, acc);
    }
    out[(size_t)row * DOUT + c] = acc;
}

extern "C" void kernel_launch(void* const* d_in, const int* in_sizes, int n_in,
                              void* d_out, int out_size, void* d_ws, size_t ws_size,
                              hipStream_t stream)
{
    const float* H      = (const float*)d_in[0];
    const float* W      = (const float*)d_in[1];
    const int*   rowPtr = (const int*)d_in[2];
    const int*   colIdx = (const int*)d_in[3];
    const float* val    = (const float*)d_in[4];
    float*       out    = (float*)d_out;

    const int n = in_sizes[2] - 1;           // rowPtr has N+1 entries
    const size_t half_elems = (size_t)n * 16;
    const size_t need = 2 * half_elems * sizeof(unsigned short);

    if (ws_size >= need && n >= 16) {
        unsigned short* tbl0 = (unsigned short*)d_ws;
        unsigned short* tbl1 = tbl0 + half_elems;
        gemm_mfma_kernel<<<(n + 63) / 64, 256, 0, stream>>>(H, W, tbl0, tbl1, n);
        const int spmm_blocks = (n + SROWS - 1) / SROWS;
        spmm_half_kernel<<<spmm_blocks, 256, 0, stream>>>(tbl0, rowPtr, colIdx, val, out, n, 0);
        spmm_half_kernel<<<spmm_blocks, 256, 0, stream>>>(tbl1, rowPtr, colIdx, val, out, n, 1);
    } else {
        const int blocks = (int)(((size_t)n * DOUT + 255) / 256);
        fused_kernel<<<blocks, 256, 0, stream>>>(H, W, rowPtr, colIdx, val, out, n);
    }
}